// Round 1
// baseline (24433.762 us; speedup 1.0000x reference)
//
#include <hip/hip_runtime.h>
#include <math.h>

#define NMAT   16384
#define CHEB_A 0.07
#define CHEB_B 9.0
#define DDEG   41            // Chebyshev degree; coefficients c_0..c_41
#define NCOEF  (DDEG + 1)

// ws float layout: gq@0 (G^{-1/2}), gsq@1024 (G^{1/2}), cheb@2048 (64), cmat@2112, cmatT@3136
#define WS_GQ    0
#define WS_GSQ   1024
#define WS_CHEB  2048
#define WS_C     2112
#define WS_CT    3136

// d_out float scratch layout (consumed before final kernel overwrites):
#define OUT_PA   0          // 256*1024  (stage-1 partial sums of X)
#define OUT_PL   262144     // 1024*1024 (stage-3 partial sums of log)
#define OUT_PL2  1310720    // 32*1024

// ---------------- block-level 32x32 matmul on LDS (row-major), 256 threads ----------------
// caller handles __syncthreads() around calls.
__device__ __forceinline__ void mm32(const float* A, const float* B, float* D, int t) {
    int i = t >> 3, j0 = (t & 7) * 4;
    float a[32];
#pragma unroll
    for (int q = 0; q < 8; ++q) {
        float4 v = *(const float4*)&A[i * 32 + q * 4];
        a[4 * q] = v.x; a[4 * q + 1] = v.y; a[4 * q + 2] = v.z; a[4 * q + 3] = v.w;
    }
    float ax = 0.f, ay = 0.f, az = 0.f, aw = 0.f;
#pragma unroll
    for (int k = 0; k < 32; ++k) {
        float4 bv = *(const float4*)&B[k * 32 + j0];
        ax += a[k] * bv.x; ay += a[k] * bv.y; az += a[k] * bv.z; aw += a[k] * bv.w;
    }
    float4 r = { ax, ay, az, aw };
    *(float4*)&D[i * 32 + j0] = r;
}

// ---------------- K1: partial sums (256 blocks x 64 matrices) ----------------
__global__ __launch_bounds__(256) void k_psum(const float4* __restrict__ X4,
                                              float4* __restrict__ pA4) {
    int b = blockIdx.x, t = threadIdx.x;
    float4 acc = { 0.f, 0.f, 0.f, 0.f };
    for (int r = 0; r < 64; ++r) {
        float4 v = X4[(size_t)(b * 64 + r) * 256 + t];
        acc.x += v.x; acc.y += v.y; acc.z += v.z; acc.w += v.w;
    }
    pA4[b * 256 + t] = acc;
}

// ---------------- K2: finalize G, compute G^{1/2}, G^{-1/2}, Chebyshev coefficients ----------------
__global__ __launch_bounds__(256) void k_setup(const float4* __restrict__ pA4,
                                               float* __restrict__ ws) {
    __shared__ alignas(16) float sG[1024], sE[1024], sPa[1024], sPb[1024], sS1[1024], sS2[1024];
    __shared__ float sc[2];
    int t = threadIdx.x;
    float4 acc = { 0.f, 0.f, 0.f, 0.f };
    for (int b = 0; b < 256; ++b) {
        float4 v = pA4[b * 256 + t];
        acc.x += v.x; acc.y += v.y; acc.z += v.z; acc.w += v.w;
    }
    const float invM = 1.0f / (float)NMAT;
    sG[4 * t + 0] = acc.x * invM; sG[4 * t + 1] = acc.y * invM;
    sG[4 * t + 2] = acc.z * invM; sG[4 * t + 3] = acc.w * invM;
    __syncthreads();
    if (t == 0) { float s = 0.f; for (int d = 0; d < 32; ++d) s += sG[d * 33]; sc[0] = s / 32.0f; }
    __syncthreads();
    float c = sc[0];
    int i = t >> 3, j0 = (t & 7) * 4;
#pragma unroll
    for (int q = 0; q < 4; ++q) {
        int e = i * 32 + j0 + q;
        sE[e] = sG[e] / c - ((i == j0 + q) ? 1.f : 0.f);
    }
    __syncthreads();
    // (1+x)^{1/2} and (1+x)^{-1/2} series coefficients
    const float alp[9] = { 1.f, 0.5f, -0.125f, 0.0625f, -0.0390625f, 0.02734375f,
                           -0.0205078125f, 0.01611328125f, -0.013092041015625f };
    const float bet[9] = { 1.f, -0.5f, 0.375f, -0.3125f, 0.2734375f, -0.24609375f,
                           0.2255859375f, -0.20947265625f, 0.196380615234375f };
#pragma unroll
    for (int q = 0; q < 4; ++q) {
        int e = i * 32 + j0 + q;
        float d = (i == j0 + q) ? 1.f : 0.f;
        sS1[e] = d + alp[1] * sE[e];
        sS2[e] = d + bet[1] * sE[e];
        sPa[e] = sE[e];
    }
    __syncthreads();
    {
        float* P = sPa; float* Pn = sPb;
        for (int k = 2; k <= 8; ++k) {
            mm32(P, sE, Pn, t);
            __syncthreads();
#pragma unroll
            for (int q = 0; q < 4; ++q) {
                int e = i * 32 + j0 + q;
                sS1[e] += alp[k] * Pn[e];
                sS2[e] += bet[k] * Pn[e];
            }
            float* tmp = P; P = Pn; Pn = tmp;
            __syncthreads();
        }
    }
    float rc = sqrtf(c);
#pragma unroll
    for (int q = 0; q < 4; ++q) {
        int e = i * 32 + j0 + q;
        ws[WS_GSQ + e] = rc * sS1[e];
        ws[WS_GQ + e]  = sS2[e] / rc;
    }
    // Chebyshev coefficients of log(x) on [CHEB_A, CHEB_B] (256-node quadrature, fp64)
    if (t < NCOEF) {
        double s = 0.0;
        const double PI = 3.14159265358979323846;
        for (int j = 0; j < 256; ++j) {
            double th = (j + 0.5) * (PI / 256.0);
            double x = 0.5 * (CHEB_B - CHEB_A) * cos(th) + 0.5 * (CHEB_B + CHEB_A);
            s += log(x) * cos((double)t * th);
        }
        ws[WS_CHEB + t] = (float)(s * (2.0 / 256.0));
    }
}

// ---------------- K3: sum of matrix logs via Clenshaw (the hot kernel) ----------------
__global__ __launch_bounds__(256) void k_logsum(const float* __restrict__ Xg,
                                                const float* __restrict__ ws,
                                                float* __restrict__ pL) {
    __shared__ alignas(16) float sGq[1024];
    __shared__ alignas(16) float sT[8 * 1152];   // 4 waves x 2 matrices, pad-36 columns
    __shared__ float sLacc[1024];
    int t = threadIdx.x;
    for (int e = t; e < 1024; e += 256) { sGq[e] = ws[WS_GQ + e]; sLacc[e] = 0.f; }
    __syncthreads();
    int wv = t >> 6, lane = t & 63, half = lane >> 5, col = lane & 31;
    float* myT = &sT[(wv * 2 + half) * 1152];
    const float* cheb = ws + WS_CHEB;
    float Lacc[32];
#pragma unroll
    for (int i = 0; i < 32; ++i) Lacc[i] = 0.f;

    for (int pass = 0; pass < 2; ++pass) {
        int m = (blockIdx.x * 4 + wv) * 4 + pass * 2 + half;
        const float* Xm = Xg + (size_t)m * 1024;
        // load X column `col`
        float xc[32];
#pragma unroll
        for (int i = 0; i < 32; ++i) xc[i] = Xm[i * 32 + col];
        // T = Gq * X  (column): tc[i] = sum_k Gq[i][k] * xc[k];  Gq symmetric -> Gq[i][k]=sGq[k*32+i]
        float tc[32];
#pragma unroll
        for (int i = 0; i < 32; ++i) tc[i] = 0.f;
#pragma unroll
        for (int k = 0; k < 32; ++k) {
            float xk = xc[k];
#pragma unroll
            for (int q = 0; q < 8; ++q) {
                float4 g = *(const float4*)&sGq[k * 32 + 4 * q];
                tc[4 * q] += g.x * xk; tc[4 * q + 1] += g.y * xk;
                tc[4 * q + 2] += g.z * xk; tc[4 * q + 3] += g.w * xk;
            }
        }
#pragma unroll
        for (int i = 0; i < 32; ++i) myT[col * 36 + i] = tc[i];
        __syncthreads();
        // S column = T * Gq:  sc2[i] = sum_k T[i][k] * Gq[k][col],  T[i][k] = myT[k*36+i]
        float sc2[32];
#pragma unroll
        for (int i = 0; i < 32; ++i) sc2[i] = 0.f;
#pragma unroll
        for (int k = 0; k < 32; ++k) {
            float gk = sGq[k * 32 + col];
#pragma unroll
            for (int q = 0; q < 8; ++q) {
                float4 tv = *(const float4*)&myT[k * 36 + 4 * q];
                sc2[4 * q] += tv.x * gk; sc2[4 * q + 1] += tv.y * gk;
                sc2[4 * q + 2] += tv.z * gk; sc2[4 * q + 3] += tv.w * gk;
            }
        }
        __syncthreads();
        // Shat = (2S - (a+b)I)/(b-a), store columns to myT
        const float m2 = 2.0f / (float)(CHEB_B - CHEB_A);
        const float sh = (float)((CHEB_A + CHEB_B) / (CHEB_B - CHEB_A));
#pragma unroll
        for (int i = 0; i < 32; ++i)
            myT[col * 36 + i] = m2 * sc2[i] - ((i == col) ? sh : 0.f);
        __syncthreads();
        // Clenshaw: b_k = c_k I + 2*Shat*b_{k+1} - b_{k+2}, in-place pairs
        float b0[32], b1[32];
        float cD = cheb[DDEG];
#pragma unroll
        for (int i = 0; i < 32; ++i) { b0[i] = (i == col) ? cD : 0.f; b1[i] = 0.f; }
        for (int k = DDEG - 1; k >= 1; k -= 2) {
            float ck = cheb[k];
#pragma unroll
            for (int i = 0; i < 32; ++i) b1[i] = ((i == col) ? ck : 0.f) - b1[i];
#pragma unroll
            for (int kk = 0; kk < 32; ++kk) {
                float bb = 2.f * b0[kk];
#pragma unroll
                for (int q = 0; q < 8; ++q) {
                    float4 sv = *(const float4*)&myT[kk * 36 + 4 * q];
                    b1[4 * q] += sv.x * bb; b1[4 * q + 1] += sv.y * bb;
                    b1[4 * q + 2] += sv.z * bb; b1[4 * q + 3] += sv.w * bb;
                }
            }
            float ck2 = cheb[k - 1];
#pragma unroll
            for (int i = 0; i < 32; ++i) b0[i] = ((i == col) ? ck2 : 0.f) - b0[i];
#pragma unroll
            for (int kk = 0; kk < 32; ++kk) {
                float bb = 2.f * b1[kk];
#pragma unroll
                for (int q = 0; q < 8; ++q) {
                    float4 sv = *(const float4*)&myT[kk * 36 + 4 * q];
                    b0[4 * q] += sv.x * bb; b0[4 * q + 1] += sv.y * bb;
                    b0[4 * q + 2] += sv.z * bb; b0[4 * q + 3] += sv.w * bb;
                }
            }
        }
        // final: f = 0.5*c0 I + Shat*b_1 - b_2   (current=b0, prev=b1)
        float c0h = 0.5f * cheb[0];
#pragma unroll
        for (int i = 0; i < 32; ++i) b1[i] = ((i == col) ? c0h : 0.f) - b1[i];
#pragma unroll
        for (int kk = 0; kk < 32; ++kk) {
            float bb = b0[kk];
#pragma unroll
            for (int q = 0; q < 8; ++q) {
                float4 sv = *(const float4*)&myT[kk * 36 + 4 * q];
                b1[4 * q] += sv.x * bb; b1[4 * q + 1] += sv.y * bb;
                b1[4 * q + 2] += sv.z * bb; b1[4 * q + 3] += sv.w * bb;
            }
        }
#pragma unroll
        for (int i = 0; i < 32; ++i) Lacc[i] += b1[i];
        __syncthreads();   // before next pass overwrites myT
    }
#pragma unroll
    for (int i = 0; i < 32; ++i) atomicAdd(&sLacc[i * 32 + col], Lacc[i]);
    __syncthreads();
    float4 v = *(float4*)&sLacc[4 * t];
    ((float4*)pL)[(size_t)blockIdx.x * 256 + t] = v;
}

// ---------------- K3b: reduce 1024 partials -> 32 ----------------
__global__ __launch_bounds__(256) void k_red32(const float4* __restrict__ pL4,
                                               float4* __restrict__ pL24) {
    int b = blockIdx.x, t = threadIdx.x;
    float4 acc = { 0.f, 0.f, 0.f, 0.f };
    for (int r = 0; r < 32; ++r) {
        float4 v = pL4[(size_t)(b * 32 + r) * 256 + t];
        acc.x += v.x; acc.y += v.y; acc.z += v.z; acc.w += v.w;
    }
    pL24[b * 256 + t] = acc;
}

// ---------------- K4: L -> expL -> Gn -> Gn^{-1/2}; W^{1/2}; C = Wsq*Gn_isq ----------------
__global__ __launch_bounds__(256) void k_final(const float4* __restrict__ pL24,
                                               const float* __restrict__ Wg,
                                               float* __restrict__ ws) {
    __shared__ alignas(16) float B0[1024], B1[1024], B2[1024], B3[1024], B4[1024], B5[1024], B6[1024];
    __shared__ float sc[4];
    int t = threadIdx.x;
    int i = t >> 3, j0 = (t & 7) * 4;
    if (t == 0) { sc[2] = 0.f; }
    // L = sum/NMAT
    float4 acc = { 0.f, 0.f, 0.f, 0.f };
    for (int b = 0; b < 32; ++b) {
        float4 v = pL24[b * 256 + t];
        acc.x += v.x; acc.y += v.y; acc.z += v.z; acc.w += v.w;
    }
    const float invM = 1.0f / (float)NMAT;
    B0[4 * t + 0] = acc.x * invM; B0[4 * t + 1] = acc.y * invM;
    B0[4 * t + 2] = acc.z * invM; B0[4 * t + 3] = acc.w * invM;
    __syncthreads();
    if (t == 0) { float s = 0.f; for (int d = 0; d < 32; ++d) s += B0[d * 33]; sc[0] = s / 32.0f; }
    __syncthreads();
    float s0 = sc[0];
#pragma unroll
    for (int q = 0; q < 4; ++q) {
        int e = i * 32 + j0 + q;
        B1[e] = B0[e] - ((i == j0 + q) ? s0 : 0.f);   // L0
    }
    __syncthreads();
    // exp series: S = I + L0 + sum_{k>=2} L0^k/k!
#pragma unroll
    for (int q = 0; q < 4; ++q) {
        int e = i * 32 + j0 + q;
        float d = (i == j0 + q) ? 1.f : 0.f;
        B2[e] = B1[e];
        B4[e] = d + B1[e];
    }
    __syncthreads();
    {
        float* P = B2; float* Pn = B3;
        for (int k = 2; k <= 14; ++k) {
            mm32(P, B1, Pn, t);
            __syncthreads();
            float invk = 1.0f / (float)k;
#pragma unroll
            for (int q = 0; q < 4; ++q) {
                int e = i * 32 + j0 + q;
                Pn[e] *= invk;
                B4[e] += Pn[e];
            }
            float* tmp = P; P = Pn; Pn = tmp;
            __syncthreads();
        }
    }
    float es = expf(s0);
#pragma unroll
    for (int q = 0; q < 4; ++q) B4[i * 32 + j0 + q] *= es;   // expL
    __syncthreads();
    for (int e = t; e < 1024; e += 256) B5[e] = ws[WS_GSQ + e];
    __syncthreads();
    mm32(B5, B4, B6, t); __syncthreads();
    mm32(B6, B5, B0, t); __syncthreads();                    // Gn in B0
    if (t == 0) { float s = 0.f; for (int d = 0; d < 32; ++d) s += B0[d * 33]; sc[1] = s / 32.0f; }
    __syncthreads();
    float c2 = sc[1];
#pragma unroll
    for (int q = 0; q < 4; ++q) {
        int e = i * 32 + j0 + q;
        B2[e] = B0[e] / c2;
        B3[e] = (i == j0 + q) ? 1.f : 0.f;
    }
    __syncthreads();
    {   // coupled NS for Gn/c2: Y->sqrt, Z->rsqrt
        float* Y = B2; float* Z = B3; float* T = B6; float* Ya = B1; float* Zb = B4;
        for (int it = 0; it < 10; ++it) {
            mm32(Z, Y, T, t); __syncthreads();
#pragma unroll
            for (int q = 0; q < 4; ++q) {
                int e = i * 32 + j0 + q;
                T[e] = 0.5f * (3.f * ((i == j0 + q) ? 1.f : 0.f) - T[e]);
            }
            __syncthreads();
            mm32(Y, T, Ya, t); mm32(T, Z, Zb, t); __syncthreads();
            float* tmp = Y; Y = Ya; Ya = tmp;
            tmp = Z; Z = Zb; Zb = tmp;
        }
        float rc2 = rsqrtf(c2);
#pragma unroll
        for (int q = 0; q < 4; ++q) {
            int e = i * 32 + j0 + q;
            B5[e] = Z[e] * rc2;      // Gn^{-1/2} (B5: Gsq dead)
        }
    }
    __syncthreads();
    // W^{1/2} via NS with Frobenius normalization
    for (int e = t; e < 1024; e += 256) B0[e] = Wg[e];
    __syncthreads();
    {
        float ls = 0.f;
#pragma unroll
        for (int q = 0; q < 4; ++q) { float w = B0[i * 32 + j0 + q]; ls += w * w; }
        atomicAdd(&sc[2], ls);
    }
    __syncthreads();
    float c3 = sqrtf(sc[2]);
#pragma unroll
    for (int q = 0; q < 4; ++q) {
        int e = i * 32 + j0 + q;
        B2[e] = B0[e] / c3;
        B3[e] = (i == j0 + q) ? 1.f : 0.f;
    }
    __syncthreads();
    {
        float* Y = B2; float* Z = B3; float* T = B6; float* Ya = B1; float* Zb = B4;
        for (int it = 0; it < 16; ++it) {
            mm32(Z, Y, T, t); __syncthreads();
#pragma unroll
            for (int q = 0; q < 4; ++q) {
                int e = i * 32 + j0 + q;
                T[e] = 0.5f * (3.f * ((i == j0 + q) ? 1.f : 0.f) - T[e]);
            }
            __syncthreads();
            mm32(Y, T, Ya, t); mm32(T, Z, Zb, t); __syncthreads();
            float* tmp = Y; Y = Ya; Ya = tmp;
            tmp = Z; Z = Zb; Zb = tmp;
        }
        float rc3 = sqrtf(c3);
#pragma unroll
        for (int q = 0; q < 4; ++q) {
            int e = i * 32 + j0 + q;
            B0[e] = Y[e] * rc3;      // W^{1/2}
        }
    }
    __syncthreads();
    mm32(B0, B5, B6, t); __syncthreads();   // C = Wsq * Gn_isq
#pragma unroll
    for (int q = 0; q < 4; ++q) {
        int e = i * 32 + j0 + q;
        ws[WS_C + e] = B6[e];
        ws[WS_CT + (j0 + q) * 32 + i] = B6[e];
    }
}

// ---------------- K5: out = C * X * C^T ----------------
__global__ __launch_bounds__(256) void k_out(const float* __restrict__ Xg,
                                             const float* __restrict__ ws,
                                             float* __restrict__ Og) {
    __shared__ alignas(16) float sCT[1024];
    __shared__ alignas(16) float sX[1024];
    __shared__ alignas(16) float sTt[33 * 32];
    int t = threadIdx.x;
    int i = t >> 3, j0 = (t & 7) * 4;
    for (int e = t; e < 1024; e += 256) sCT[e] = ws[WS_CT + e];
    __syncthreads();
    for (int r = 0; r < 8; ++r) {
        int m = blockIdx.x * 8 + r;
        const float4* Xm4 = (const float4*)(Xg + (size_t)m * 1024);
        *(float4*)&sX[4 * t] = Xm4[t];
        __syncthreads();
        // T1[i][j] = sum_k C[i][k] X[k][j] = sum_k CT[k*32+i] * X[k][j]; store transposed+pad
        float ax = 0.f, ay = 0.f, az = 0.f, aw = 0.f;
#pragma unroll
        for (int k = 0; k < 32; ++k) {
            float cv = sCT[k * 32 + i];
            float4 xv = *(const float4*)&sX[k * 32 + j0];
            ax += cv * xv.x; ay += cv * xv.y; az += cv * xv.z; aw += cv * xv.w;
        }
        sTt[(j0 + 0) * 33 + i] = ax; sTt[(j0 + 1) * 33 + i] = ay;
        sTt[(j0 + 2) * 33 + i] = az; sTt[(j0 + 3) * 33 + i] = aw;
        __syncthreads();
        // out[i][j] = sum_k T1[i][k] C[j][k] = sum_k sTt[k*33+i] * CT[k*32+j]
        ax = ay = az = aw = 0.f;
#pragma unroll
        for (int k = 0; k < 32; ++k) {
            float tv = sTt[k * 33 + i];
            float4 cv = *(const float4*)&sCT[k * 32 + j0];
            ax += tv * cv.x; ay += tv * cv.y; az += tv * cv.z; aw += tv * cv.w;
        }
        float4 r4 = { ax, ay, az, aw };
        *(float4*)&Og[(size_t)m * 1024 + i * 32 + j0] = r4;
        __syncthreads();
    }
}

extern "C" void kernel_launch(void* const* d_in, const int* in_sizes, int n_in,
                              void* d_out, int out_size, void* d_ws, size_t ws_size,
                              hipStream_t stream) {
    const float* X = (const float*)d_in[0];
    const float* W = (const float*)d_in[1];
    float* out = (float*)d_out;
    float* ws  = (float*)d_ws;
    float* pA  = out + OUT_PA;
    float* pL  = out + OUT_PL;
    float* pL2 = out + OUT_PL2;

    hipLaunchKernelGGL(k_psum,   dim3(256),  dim3(256), 0, stream, (const float4*)X, (float4*)pA);
    hipLaunchKernelGGL(k_setup,  dim3(1),    dim3(256), 0, stream, (const float4*)pA, ws);
    hipLaunchKernelGGL(k_logsum, dim3(1024), dim3(256), 0, stream, X, ws, pL);
    hipLaunchKernelGGL(k_red32,  dim3(32),   dim3(256), 0, stream, (const float4*)pL, (float4*)pL2);
    hipLaunchKernelGGL(k_final,  dim3(1),    dim3(256), 0, stream, (const float4*)pL2, W, ws);
    hipLaunchKernelGGL(k_out,    dim3(2048), dim3(256), 0, stream, X, ws, out);
}

// Round 2
// 17006.631 us; speedup vs baseline: 1.4367x; 1.4367x over previous
//
#include <hip/hip_runtime.h>
#include <math.h>

#define NMAT   16384
#define CHEB_A 0.08
#define CHEB_B 7.0
#define DDEG   37            // Chebyshev degree (odd); coefficients c_0..c_37
#define NCOEF  (DDEG + 1)

// ws float layout: gq@0 (G^{-1/2}), gsq@1024 (G^{1/2}), cheb@2048 (64), cmat@2112, cmatT@3136
#define WS_GQ    0
#define WS_GSQ   1024
#define WS_CHEB  2048
#define WS_C     2112
#define WS_CT    3136

// d_out float scratch layout (consumed before final kernel overwrites):
#define OUT_PA   0          // 256*1024   (stage-1 partial sums of X)
#define OUT_PL   262144     // 2048*1024  (stage-3 partial sums of log)
#define OUT_PL2  2359296    // 32*1024

// ---------------- block-level 32x32 matmul on LDS (row-major), 256 threads ----------------
__device__ __forceinline__ void mm32(const float* A, const float* B, float* D, int t) {
    int i = t >> 3, j0 = (t & 7) * 4;
    float a[32];
#pragma unroll
    for (int q = 0; q < 8; ++q) {
        float4 v = *(const float4*)&A[i * 32 + q * 4];
        a[4 * q] = v.x; a[4 * q + 1] = v.y; a[4 * q + 2] = v.z; a[4 * q + 3] = v.w;
    }
    float ax = 0.f, ay = 0.f, az = 0.f, aw = 0.f;
#pragma unroll
    for (int k = 0; k < 32; ++k) {
        float4 bv = *(const float4*)&B[k * 32 + j0];
        ax += a[k] * bv.x; ay += a[k] * bv.y; az += a[k] * bv.z; aw += a[k] * bv.w;
    }
    float4 r = { ax, ay, az, aw };
    *(float4*)&D[i * 32 + j0] = r;
}

// ---------------- K1: partial sums (256 blocks x 64 matrices) ----------------
__global__ __launch_bounds__(256) void k_psum(const float4* __restrict__ X4,
                                              float4* __restrict__ pA4) {
    int b = blockIdx.x, t = threadIdx.x;
    float4 acc = { 0.f, 0.f, 0.f, 0.f };
    for (int r = 0; r < 64; ++r) {
        float4 v = X4[(size_t)(b * 64 + r) * 256 + t];
        acc.x += v.x; acc.y += v.y; acc.z += v.z; acc.w += v.w;
    }
    pA4[b * 256 + t] = acc;
}

// ---------------- K2: finalize G, G^{1/2}, G^{-1/2}, Chebyshev coefficients ----------------
__global__ __launch_bounds__(256) void k_setup(const float4* __restrict__ pA4,
                                               float* __restrict__ ws) {
    __shared__ alignas(16) float sG[1024], sE[1024], sPa[1024], sPb[1024], sS1[1024], sS2[1024];
    __shared__ float sc[2];
    int t = threadIdx.x;
    float4 acc = { 0.f, 0.f, 0.f, 0.f };
    for (int b = 0; b < 256; ++b) {
        float4 v = pA4[b * 256 + t];
        acc.x += v.x; acc.y += v.y; acc.z += v.z; acc.w += v.w;
    }
    const float invM = 1.0f / (float)NMAT;
    sG[4 * t + 0] = acc.x * invM; sG[4 * t + 1] = acc.y * invM;
    sG[4 * t + 2] = acc.z * invM; sG[4 * t + 3] = acc.w * invM;
    __syncthreads();
    if (t == 0) { float s = 0.f; for (int d = 0; d < 32; ++d) s += sG[d * 33]; sc[0] = s / 32.0f; }
    __syncthreads();
    float c = sc[0];
    int i = t >> 3, j0 = (t & 7) * 4;
#pragma unroll
    for (int q = 0; q < 4; ++q) {
        int e = i * 32 + j0 + q;
        sE[e] = sG[e] / c - ((i == j0 + q) ? 1.f : 0.f);
    }
    __syncthreads();
    const float alp[9] = { 1.f, 0.5f, -0.125f, 0.0625f, -0.0390625f, 0.02734375f,
                           -0.0205078125f, 0.01611328125f, -0.013092041015625f };
    const float bet[9] = { 1.f, -0.5f, 0.375f, -0.3125f, 0.2734375f, -0.24609375f,
                           0.2255859375f, -0.20947265625f, 0.196380615234375f };
#pragma unroll
    for (int q = 0; q < 4; ++q) {
        int e = i * 32 + j0 + q;
        float d = (i == j0 + q) ? 1.f : 0.f;
        sS1[e] = d + alp[1] * sE[e];
        sS2[e] = d + bet[1] * sE[e];
        sPa[e] = sE[e];
    }
    __syncthreads();
    {
        float* P = sPa; float* Pn = sPb;
        for (int k = 2; k <= 8; ++k) {
            mm32(P, sE, Pn, t);
            __syncthreads();
#pragma unroll
            for (int q = 0; q < 4; ++q) {
                int e = i * 32 + j0 + q;
                sS1[e] += alp[k] * Pn[e];
                sS2[e] += bet[k] * Pn[e];
            }
            float* tmp = P; P = Pn; Pn = tmp;
            __syncthreads();
        }
    }
    float rc = sqrtf(c);
#pragma unroll
    for (int q = 0; q < 4; ++q) {
        int e = i * 32 + j0 + q;
        ws[WS_GSQ + e] = rc * sS1[e];
        ws[WS_GQ + e]  = sS2[e] / rc;
    }
    if (t < NCOEF) {
        double s = 0.0;
        const double PI = 3.14159265358979323846;
        for (int j = 0; j < 256; ++j) {
            double th = (j + 0.5) * (PI / 256.0);
            double x = 0.5 * (CHEB_B - CHEB_A) * cos(th) + 0.5 * (CHEB_B + CHEB_A);
            s += log(x) * cos((double)t * th);
        }
        ws[WS_CHEB + t] = (float)(s * (2.0 / 256.0));
    }
}

// ---------------- K3: sum of matrix logs via Clenshaw (the hot kernel) ----------------
// 2048 blocks, 8 matrices each (4 waves x 2 half-waves). Spill-free layout:
// one reusable acc[32] for staging, b0/b1[32] for Clenshaw, no persistent Lacc.
__global__ __launch_bounds__(256, 3) void k_logsum(const float* __restrict__ Xg,
                                                   const float* __restrict__ ws,
                                                   float* __restrict__ pL) {
    __shared__ alignas(16) float sGq[1024];
    __shared__ alignas(16) float sT[8 * 1152];   // 4 waves x 2 matrices, pad-36 columns
    __shared__ float sLacc[1024];
    int t = threadIdx.x;
    for (int e = t; e < 1024; e += 256) { sGq[e] = ws[WS_GQ + e]; sLacc[e] = 0.f; }
    __syncthreads();
    int wv = t >> 6, lane = t & 63, half = lane >> 5, col = lane & 31;
    float* myT = &sT[(wv * 2 + half) * 1152];
    const float* cheb = ws + WS_CHEB;
    int m = blockIdx.x * 8 + wv * 2 + half;
    const float* Xm = Xg + (size_t)m * 1024;

    // ---- phase A: T = Gq*X column: acc[i] = sum_k Gq[i][k]*X[k][col]; Gq sym -> col k contiguous
    float acc[32];
#pragma unroll
    for (int i = 0; i < 32; ++i) acc[i] = 0.f;
    for (int k4 = 0; k4 < 32; k4 += 4) {
        float xk[4];
#pragma unroll
        for (int u = 0; u < 4; ++u) xk[u] = Xm[(k4 + u) * 32 + col];
#pragma unroll
        for (int u = 0; u < 4; ++u) {
#pragma unroll
            for (int q = 0; q < 8; ++q) {
                float4 g = *(const float4*)&sGq[(k4 + u) * 32 + 4 * q];
                acc[4 * q + 0] += g.x * xk[u]; acc[4 * q + 1] += g.y * xk[u];
                acc[4 * q + 2] += g.z * xk[u]; acc[4 * q + 3] += g.w * xk[u];
            }
        }
    }
#pragma unroll
    for (int i = 0; i < 32; ++i) myT[col * 36 + i] = acc[i];
    __syncthreads();

    // ---- phase B: S column = T*Gq: acc[i] = sum_k T[i][k]*Gq[k][col]; T[i][k] at myT[k*36+i]
#pragma unroll
    for (int i = 0; i < 32; ++i) acc[i] = 0.f;
    for (int k = 0; k < 32; ++k) {
        float gk = sGq[k * 32 + col];
#pragma unroll
        for (int q = 0; q < 8; ++q) {
            float4 tv = *(const float4*)&myT[k * 36 + 4 * q];
            acc[4 * q + 0] += tv.x * gk; acc[4 * q + 1] += tv.y * gk;
            acc[4 * q + 2] += tv.z * gk; acc[4 * q + 3] += tv.w * gk;
        }
    }
    __syncthreads();
    const float m2 = 2.0f / (float)(CHEB_B - CHEB_A);
    const float sh = (float)((CHEB_A + CHEB_B) / (CHEB_B - CHEB_A));
#pragma unroll
    for (int i = 0; i < 32; ++i)
        myT[col * 36 + i] = m2 * acc[i] - ((i == col) ? sh : 0.f);
    __syncthreads();

    // ---- Clenshaw: b_k = c_k I + 2*Shat*b_{k+1} - b_{k+2}
    float b0[32], b1[32];
    float cD = cheb[DDEG];
#pragma unroll
    for (int i = 0; i < 32; ++i) { b0[i] = (i == col) ? cD : 0.f; b1[i] = 0.f; }
    for (int k = DDEG - 1; k >= 1; k -= 2) {
        float ck = cheb[k];
#pragma unroll
        for (int i = 0; i < 32; ++i) b1[i] = ((i == col) ? ck : 0.f) - b1[i];
#pragma unroll
        for (int kk = 0; kk < 32; ++kk) {
            float bb = 2.f * b0[kk];
#pragma unroll
            for (int q = 0; q < 8; ++q) {
                float4 sv = *(const float4*)&myT[kk * 36 + 4 * q];
                b1[4 * q + 0] += sv.x * bb; b1[4 * q + 1] += sv.y * bb;
                b1[4 * q + 2] += sv.z * bb; b1[4 * q + 3] += sv.w * bb;
            }
        }
        float ck2 = cheb[k - 1];
#pragma unroll
        for (int i = 0; i < 32; ++i) b0[i] = ((i == col) ? ck2 : 0.f) - b0[i];
#pragma unroll
        for (int kk = 0; kk < 32; ++kk) {
            float bb = 2.f * b1[kk];
#pragma unroll
            for (int q = 0; q < 8; ++q) {
                float4 sv = *(const float4*)&myT[kk * 36 + 4 * q];
                b0[4 * q + 0] += sv.x * bb; b0[4 * q + 1] += sv.y * bb;
                b0[4 * q + 2] += sv.z * bb; b0[4 * q + 3] += sv.w * bb;
            }
        }
    }
    // final: f = 0.5*c0 I - b_2 + Shat*b_1   (current=b0 is b_1, prev=b1 is b_2)
    float c0h = 0.5f * cheb[0];
#pragma unroll
    for (int i = 0; i < 32; ++i) b1[i] = ((i == col) ? c0h : 0.f) - b1[i];
#pragma unroll
    for (int kk = 0; kk < 32; ++kk) {
        float bb = b0[kk];
#pragma unroll
        for (int q = 0; q < 8; ++q) {
            float4 sv = *(const float4*)&myT[kk * 36 + 4 * q];
            b1[4 * q + 0] += sv.x * bb; b1[4 * q + 1] += sv.y * bb;
            b1[4 * q + 2] += sv.z * bb; b1[4 * q + 3] += sv.w * bb;
        }
    }
#pragma unroll
    for (int i = 0; i < 32; ++i) atomicAdd(&sLacc[i * 32 + col], b1[i]);
    __syncthreads();
    float4 v = *(float4*)&sLacc[4 * t];
    ((float4*)pL)[(size_t)blockIdx.x * 256 + t] = v;
}

// ---------------- K3b: reduce 2048 partials -> 32 ----------------
__global__ __launch_bounds__(256) void k_red32(const float4* __restrict__ pL4,
                                               float4* __restrict__ pL24) {
    int b = blockIdx.x, t = threadIdx.x;
    float4 acc = { 0.f, 0.f, 0.f, 0.f };
    for (int r = 0; r < 64; ++r) {
        float4 v = pL4[(size_t)(b * 64 + r) * 256 + t];
        acc.x += v.x; acc.y += v.y; acc.z += v.z; acc.w += v.w;
    }
    pL24[b * 256 + t] = acc;
}

// ---------------- K4: L -> expL -> Gn -> Gn^{-1/2}; W^{1/2}; C = Wsq*Gn_isq ----------------
__global__ __launch_bounds__(256) void k_final(const float4* __restrict__ pL24,
                                               const float* __restrict__ Wg,
                                               float* __restrict__ ws) {
    __shared__ alignas(16) float B0[1024], B1[1024], B2[1024], B3[1024], B4[1024], B5[1024], B6[1024];
    __shared__ float sc[4];
    int t = threadIdx.x;
    int i = t >> 3, j0 = (t & 7) * 4;
    if (t == 0) { sc[2] = 0.f; }
    float4 acc = { 0.f, 0.f, 0.f, 0.f };
    for (int b = 0; b < 32; ++b) {
        float4 v = pL24[b * 256 + t];
        acc.x += v.x; acc.y += v.y; acc.z += v.z; acc.w += v.w;
    }
    const float invM = 1.0f / (float)NMAT;
    B0[4 * t + 0] = acc.x * invM; B0[4 * t + 1] = acc.y * invM;
    B0[4 * t + 2] = acc.z * invM; B0[4 * t + 3] = acc.w * invM;
    __syncthreads();
    if (t == 0) { float s = 0.f; for (int d = 0; d < 32; ++d) s += B0[d * 33]; sc[0] = s / 32.0f; }
    __syncthreads();
    float s0 = sc[0];
#pragma unroll
    for (int q = 0; q < 4; ++q) {
        int e = i * 32 + j0 + q;
        B1[e] = B0[e] - ((i == j0 + q) ? s0 : 0.f);   // L0
    }
    __syncthreads();
#pragma unroll
    for (int q = 0; q < 4; ++q) {
        int e = i * 32 + j0 + q;
        float d = (i == j0 + q) ? 1.f : 0.f;
        B2[e] = B1[e];
        B4[e] = d + B1[e];
    }
    __syncthreads();
    {
        float* P = B2; float* Pn = B3;
        for (int k = 2; k <= 14; ++k) {
            mm32(P, B1, Pn, t);
            __syncthreads();
            float invk = 1.0f / (float)k;
#pragma unroll
            for (int q = 0; q < 4; ++q) {
                int e = i * 32 + j0 + q;
                Pn[e] *= invk;
                B4[e] += Pn[e];
            }
            float* tmp = P; P = Pn; Pn = tmp;
            __syncthreads();
        }
    }
    float es = expf(s0);
#pragma unroll
    for (int q = 0; q < 4; ++q) B4[i * 32 + j0 + q] *= es;   // expL
    __syncthreads();
    for (int e = t; e < 1024; e += 256) B5[e] = ws[WS_GSQ + e];
    __syncthreads();
    mm32(B5, B4, B6, t); __syncthreads();
    mm32(B6, B5, B0, t); __syncthreads();                    // Gn in B0
    if (t == 0) { float s = 0.f; for (int d = 0; d < 32; ++d) s += B0[d * 33]; sc[1] = s / 32.0f; }
    __syncthreads();
    float c2 = sc[1];
#pragma unroll
    for (int q = 0; q < 4; ++q) {
        int e = i * 32 + j0 + q;
        B2[e] = B0[e] / c2;
        B3[e] = (i == j0 + q) ? 1.f : 0.f;
    }
    __syncthreads();
    {   // coupled NS for Gn/c2: Z->rsqrt
        float* Y = B2; float* Z = B3; float* T = B6; float* Ya = B1; float* Zb = B4;
        for (int it = 0; it < 10; ++it) {
            mm32(Z, Y, T, t); __syncthreads();
#pragma unroll
            for (int q = 0; q < 4; ++q) {
                int e = i * 32 + j0 + q;
                T[e] = 0.5f * (3.f * ((i == j0 + q) ? 1.f : 0.f) - T[e]);
            }
            __syncthreads();
            mm32(Y, T, Ya, t); mm32(T, Z, Zb, t); __syncthreads();
            float* tmp = Y; Y = Ya; Ya = tmp;
            tmp = Z; Z = Zb; Zb = tmp;
        }
        float rc2 = rsqrtf(c2);
#pragma unroll
        for (int q = 0; q < 4; ++q) {
            int e = i * 32 + j0 + q;
            B5[e] = Z[e] * rc2;      // Gn^{-1/2}
        }
    }
    __syncthreads();
    for (int e = t; e < 1024; e += 256) B0[e] = Wg[e];
    __syncthreads();
    {
        float ls = 0.f;
#pragma unroll
        for (int q = 0; q < 4; ++q) { float w = B0[i * 32 + j0 + q]; ls += w * w; }
        atomicAdd(&sc[2], ls);
    }
    __syncthreads();
    float c3 = sqrtf(sc[2]);
#pragma unroll
    for (int q = 0; q < 4; ++q) {
        int e = i * 32 + j0 + q;
        B2[e] = B0[e] / c3;
        B3[e] = (i == j0 + q) ? 1.f : 0.f;
    }
    __syncthreads();
    {
        float* Y = B2; float* Z = B3; float* T = B6; float* Ya = B1; float* Zb = B4;
        for (int it = 0; it < 16; ++it) {
            mm32(Z, Y, T, t); __syncthreads();
#pragma unroll
            for (int q = 0; q < 4; ++q) {
                int e = i * 32 + j0 + q;
                T[e] = 0.5f * (3.f * ((i == j0 + q) ? 1.f : 0.f) - T[e]);
            }
            __syncthreads();
            mm32(Y, T, Ya, t); mm32(T, Z, Zb, t); __syncthreads();
            float* tmp = Y; Y = Ya; Ya = tmp;
            tmp = Z; Z = Zb; Zb = tmp;
        }
        float rc3 = sqrtf(c3);
#pragma unroll
        for (int q = 0; q < 4; ++q) {
            int e = i * 32 + j0 + q;
            B0[e] = Y[e] * rc3;      // W^{1/2}
        }
    }
    __syncthreads();
    mm32(B0, B5, B6, t); __syncthreads();   // C = Wsq * Gn_isq
#pragma unroll
    for (int q = 0; q < 4; ++q) {
        int e = i * 32 + j0 + q;
        ws[WS_C + e] = B6[e];
        ws[WS_CT + (j0 + q) * 32 + i] = B6[e];
    }
}

// ---------------- K5: out = C * X * C^T ----------------
__global__ __launch_bounds__(256) void k_out(const float* __restrict__ Xg,
                                             const float* __restrict__ ws,
                                             float* __restrict__ Og) {
    __shared__ alignas(16) float sCT[1024];
    __shared__ alignas(16) float sX[1024];
    __shared__ alignas(16) float sTt[33 * 32];
    int t = threadIdx.x;
    int i = t >> 3, j0 = (t & 7) * 4;
    for (int e = t; e < 1024; e += 256) sCT[e] = ws[WS_CT + e];
    __syncthreads();
    for (int r = 0; r < 8; ++r) {
        int m = blockIdx.x * 8 + r;
        const float4* Xm4 = (const float4*)(Xg + (size_t)m * 1024);
        *(float4*)&sX[4 * t] = Xm4[t];
        __syncthreads();
        float ax = 0.f, ay = 0.f, az = 0.f, aw = 0.f;
#pragma unroll
        for (int k = 0; k < 32; ++k) {
            float cv = sCT[k * 32 + i];
            float4 xv = *(const float4*)&sX[k * 32 + j0];
            ax += cv * xv.x; ay += cv * xv.y; az += cv * xv.z; aw += cv * xv.w;
        }
        sTt[(j0 + 0) * 33 + i] = ax; sTt[(j0 + 1) * 33 + i] = ay;
        sTt[(j0 + 2) * 33 + i] = az; sTt[(j0 + 3) * 33 + i] = aw;
        __syncthreads();
        ax = ay = az = aw = 0.f;
#pragma unroll
        for (int k = 0; k < 32; ++k) {
            float tv = sTt[k * 33 + i];
            float4 cv = *(const float4*)&sCT[k * 32 + j0];
            ax += tv * cv.x; ay += tv * cv.y; az += tv * cv.z; aw += tv * cv.w;
        }
        float4 r4 = { ax, ay, az, aw };
        *(float4*)&Og[(size_t)m * 1024 + i * 32 + j0] = r4;
        __syncthreads();
    }
}

extern "C" void kernel_launch(void* const* d_in, const int* in_sizes, int n_in,
                              void* d_out, int out_size, void* d_ws, size_t ws_size,
                              hipStream_t stream) {
    const float* X = (const float*)d_in[0];
    const float* W = (const float*)d_in[1];
    float* out = (float*)d_out;
    float* ws  = (float*)d_ws;
    float* pA  = out + OUT_PA;
    float* pL  = out + OUT_PL;
    float* pL2 = out + OUT_PL2;

    hipLaunchKernelGGL(k_psum,   dim3(256),  dim3(256), 0, stream, (const float4*)X, (float4*)pA);
    hipLaunchKernelGGL(k_setup,  dim3(1),    dim3(256), 0, stream, (const float4*)pA, ws);
    hipLaunchKernelGGL(k_logsum, dim3(2048), dim3(256), 0, stream, X, ws, pL);
    hipLaunchKernelGGL(k_red32,  dim3(32),   dim3(256), 0, stream, (const float4*)pL, (float4*)pL2);
    hipLaunchKernelGGL(k_final,  dim3(1),    dim3(256), 0, stream, (const float4*)pL2, W, ws);
    hipLaunchKernelGGL(k_out,    dim3(2048), dim3(256), 0, stream, X, ws, out);
}

// Round 3
// 1166.645 us; speedup vs baseline: 20.9436x; 14.5774x over previous
//
#include <hip/hip_runtime.h>
#include <math.h>

#define NMAT   16384
#define CHEB_A 0.08
#define CHEB_B 7.0
#define DDEG   37            // Chebyshev degree (odd); coefficients c_0..c_37
#define NCOEF  (DDEG + 1)

// ws float layout
#define WS_GQ    0
#define WS_GSQ   1024
#define WS_CHEB  2048
#define WS_C     2112
#define WS_CT    3136

// d_out float scratch layout (consumed before final kernel overwrites):
#define OUT_PA   0          // 256*1024   (stage-1 partial sums of X)
#define OUT_PL   262144     // 4096*1024  (stage-3 partial sums of log)
#define OUT_PL2  4456448    // 32*1024

// ---------------- block-level 32x32 matmul on LDS (row-major), 256 threads ----------------
__device__ __forceinline__ void mm32(const float* A, const float* B, float* D, int t) {
    int i = t >> 3, j0 = (t & 7) * 4;
    float a[32];
#pragma unroll
    for (int q = 0; q < 8; ++q) {
        float4 v = *(const float4*)&A[i * 32 + q * 4];
        a[4 * q] = v.x; a[4 * q + 1] = v.y; a[4 * q + 2] = v.z; a[4 * q + 3] = v.w;
    }
    float ax = 0.f, ay = 0.f, az = 0.f, aw = 0.f;
#pragma unroll
    for (int k = 0; k < 32; ++k) {
        float4 bv = *(const float4*)&B[k * 32 + j0];
        ax += a[k] * bv.x; ay += a[k] * bv.y; az += a[k] * bv.z; aw += a[k] * bv.w;
    }
    float4 r = { ax, ay, az, aw };
    *(float4*)&D[i * 32 + j0] = r;
}

// ---------------- K1: partial sums (256 blocks x 64 matrices) ----------------
__global__ __launch_bounds__(256) void k_psum(const float4* __restrict__ X4,
                                              float4* __restrict__ pA4) {
    int b = blockIdx.x, t = threadIdx.x;
    float4 acc = { 0.f, 0.f, 0.f, 0.f };
    for (int r = 0; r < 64; ++r) {
        float4 v = X4[(size_t)(b * 64 + r) * 256 + t];
        acc.x += v.x; acc.y += v.y; acc.z += v.z; acc.w += v.w;
    }
    pA4[b * 256 + t] = acc;
}

// ---------------- K2: finalize G, G^{1/2}, G^{-1/2}, Chebyshev coefficients ----------------
__global__ __launch_bounds__(256) void k_setup(const float4* __restrict__ pA4,
                                               float* __restrict__ ws) {
    __shared__ alignas(16) float sG[1024], sE[1024], sPa[1024], sPb[1024], sS1[1024], sS2[1024];
    __shared__ float sc[2];
    int t = threadIdx.x;
    float4 acc = { 0.f, 0.f, 0.f, 0.f };
    for (int b = 0; b < 256; ++b) {
        float4 v = pA4[b * 256 + t];
        acc.x += v.x; acc.y += v.y; acc.z += v.z; acc.w += v.w;
    }
    const float invM = 1.0f / (float)NMAT;
    sG[4 * t + 0] = acc.x * invM; sG[4 * t + 1] = acc.y * invM;
    sG[4 * t + 2] = acc.z * invM; sG[4 * t + 3] = acc.w * invM;
    __syncthreads();
    if (t == 0) { float s = 0.f; for (int d = 0; d < 32; ++d) s += sG[d * 33]; sc[0] = s / 32.0f; }
    __syncthreads();
    float c = sc[0];
    int i = t >> 3, j0 = (t & 7) * 4;
#pragma unroll
    for (int q = 0; q < 4; ++q) {
        int e = i * 32 + j0 + q;
        sE[e] = sG[e] / c - ((i == j0 + q) ? 1.f : 0.f);
    }
    __syncthreads();
    const float alp[9] = { 1.f, 0.5f, -0.125f, 0.0625f, -0.0390625f, 0.02734375f,
                           -0.0205078125f, 0.01611328125f, -0.013092041015625f };
    const float bet[9] = { 1.f, -0.5f, 0.375f, -0.3125f, 0.2734375f, -0.24609375f,
                           0.2255859375f, -0.20947265625f, 0.196380615234375f };
#pragma unroll
    for (int q = 0; q < 4; ++q) {
        int e = i * 32 + j0 + q;
        float d = (i == j0 + q) ? 1.f : 0.f;
        sS1[e] = d + alp[1] * sE[e];
        sS2[e] = d + bet[1] * sE[e];
        sPa[e] = sE[e];
    }
    __syncthreads();
    {
        float* P = sPa; float* Pn = sPb;
        for (int k = 2; k <= 8; ++k) {
            mm32(P, sE, Pn, t);
            __syncthreads();
#pragma unroll
            for (int q = 0; q < 4; ++q) {
                int e = i * 32 + j0 + q;
                sS1[e] += alp[k] * Pn[e];
                sS2[e] += bet[k] * Pn[e];
            }
            float* tmp = P; P = Pn; Pn = tmp;
            __syncthreads();
        }
    }
    float rc = sqrtf(c);
#pragma unroll
    for (int q = 0; q < 4; ++q) {
        int e = i * 32 + j0 + q;
        ws[WS_GSQ + e] = rc * sS1[e];
        ws[WS_GQ + e]  = sS2[e] / rc;
    }
    if (t < NCOEF) {
        double s = 0.0;
        const double PI = 3.14159265358979323846;
        for (int j = 0; j < 256; ++j) {
            double th = (j + 0.5) * (PI / 256.0);
            double x = 0.5 * (CHEB_B - CHEB_A) * cos(th) + 0.5 * (CHEB_B + CHEB_A);
            s += log(x) * cos((double)t * th);
        }
        ws[WS_CHEB + t] = (float)(s * (2.0 / 256.0));
    }
}

// ---------------- K3: sum of matrix logs via Clenshaw (the hot kernel) ----------------
// One matrix per wave; lane (half,col) owns a 16-row fragment of column col.
// Per-lane live state: b0f[16]+b1f[16] (+temps) -> no spill. Full b-column is
// streamed through a per-wave LDS buffer (pad-33, conflict-free). Shat is
// symmetric, so its column k is read as contiguous row k (b128 broadcast).
// Wave-lockstep + in-order DS => no barriers; compiler fences stop reordering.
#define CL_HALF(dst, src, ckv, fac)                                          \
    {                                                                        \
        _Pragma("unroll")                                                    \
        for (int i = 0; i < 16; ++i)                                         \
            dst[i] = ((r0 + i) == col ? (ckv) : 0.f) - dst[i];               \
        asm volatile("" ::: "memory");                                       \
        _Pragma("unroll")                                                    \
        for (int i = 0; i < 16; ++i) bcol[col * 33 + r0 + i] = src[i];       \
        asm volatile("" ::: "memory");                                       \
        _Pragma("unroll 4")                                                  \
        for (int k = 0; k < 32; ++k) {                                       \
            float bv = (fac) * bcol[col * 33 + k];                           \
            float4 s0 = *(const float4*)&sS[k * 36 + r0 + 0];                \
            float4 s1 = *(const float4*)&sS[k * 36 + r0 + 4];                \
            float4 s2 = *(const float4*)&sS[k * 36 + r0 + 8];                \
            float4 s3 = *(const float4*)&sS[k * 36 + r0 + 12];               \
            dst[0]  += s0.x * bv; dst[1]  += s0.y * bv;                      \
            dst[2]  += s0.z * bv; dst[3]  += s0.w * bv;                      \
            dst[4]  += s1.x * bv; dst[5]  += s1.y * bv;                      \
            dst[6]  += s1.z * bv; dst[7]  += s1.w * bv;                      \
            dst[8]  += s2.x * bv; dst[9]  += s2.y * bv;                      \
            dst[10] += s2.z * bv; dst[11] += s2.w * bv;                      \
            dst[12] += s3.x * bv; dst[13] += s3.y * bv;                      \
            dst[14] += s3.z * bv; dst[15] += s3.w * bv;                      \
        }                                                                    \
    }

__global__ __launch_bounds__(256, 2) void k_logsum(const float* __restrict__ Xg,
                                                   const float* __restrict__ ws,
                                                   float* __restrict__ pL) {
    __shared__ alignas(16) float sGq[1024];
    __shared__ alignas(16) float wbuf[4 * 2304];  // per wave: Tt[1152] (pad-36; later bcol pad-33) + sS[1152]
    __shared__ float sLacc[1024];
    int t = threadIdx.x;
    for (int e = t; e < 1024; e += 256) { sGq[e] = ws[WS_GQ + e]; sLacc[e] = 0.f; }
    __syncthreads();
    const int wv = t >> 6, lane = t & 63, half = lane >> 5, col = lane & 31;
    const int r0 = half * 16;
    float* Tt   = &wbuf[wv * 2304];
    float* sS   = Tt + 1152;
    float* bcol = Tt;                 // overlays Tt (dead after phase B)
    const float* cheb = ws + WS_CHEB;
    const float* Xm = Xg + (size_t)(blockIdx.x * 4 + wv) * 1024;

    // ---- phase A: T = Gq * X ; store transposed Tt[col*36 + r] = T[r][col]
    float fa[16];
#pragma unroll
    for (int i = 0; i < 16; ++i) fa[i] = 0.f;
#pragma unroll
    for (int k = 0; k < 32; ++k) {
        float xk = Xm[k * 32 + col];
        float4 g0 = *(const float4*)&sGq[k * 32 + r0 + 0];   // Gq[r][k]=Gq[k][r] (sym)
        float4 g1 = *(const float4*)&sGq[k * 32 + r0 + 4];
        float4 g2 = *(const float4*)&sGq[k * 32 + r0 + 8];
        float4 g3 = *(const float4*)&sGq[k * 32 + r0 + 12];
        fa[0]  += g0.x * xk; fa[1]  += g0.y * xk; fa[2]  += g0.z * xk; fa[3]  += g0.w * xk;
        fa[4]  += g1.x * xk; fa[5]  += g1.y * xk; fa[6]  += g1.z * xk; fa[7]  += g1.w * xk;
        fa[8]  += g2.x * xk; fa[9]  += g2.y * xk; fa[10] += g2.z * xk; fa[11] += g2.w * xk;
        fa[12] += g3.x * xk; fa[13] += g3.y * xk; fa[14] += g3.z * xk; fa[15] += g3.w * xk;
    }
#pragma unroll
    for (int i = 0; i < 16; ++i) Tt[col * 36 + r0 + i] = fa[i];
    asm volatile("" ::: "memory");

    // ---- phase B: S = T * Gq ; Shat = m2*S - sh*I, row-major pad-36
#pragma unroll
    for (int i = 0; i < 16; ++i) fa[i] = 0.f;
#pragma unroll 4
    for (int k = 0; k < 32; ++k) {
        float gk = sGq[k * 32 + col];
        float4 t0 = *(const float4*)&Tt[k * 36 + r0 + 0];    // T[r][k] = Tt[k*36+r]
        float4 t1 = *(const float4*)&Tt[k * 36 + r0 + 4];
        float4 t2 = *(const float4*)&Tt[k * 36 + r0 + 8];
        float4 t3 = *(const float4*)&Tt[k * 36 + r0 + 12];
        fa[0]  += t0.x * gk; fa[1]  += t0.y * gk; fa[2]  += t0.z * gk; fa[3]  += t0.w * gk;
        fa[4]  += t1.x * gk; fa[5]  += t1.y * gk; fa[6]  += t1.z * gk; fa[7]  += t1.w * gk;
        fa[8]  += t2.x * gk; fa[9]  += t2.y * gk; fa[10] += t2.z * gk; fa[11] += t2.w * gk;
        fa[12] += t3.x * gk; fa[13] += t3.y * gk; fa[14] += t3.z * gk; fa[15] += t3.w * gk;
    }
    asm volatile("" ::: "memory");
    const float m2 = 2.0f / (float)(CHEB_B - CHEB_A);
    const float sh = (float)((CHEB_A + CHEB_B) / (CHEB_B - CHEB_A));
#pragma unroll
    for (int i = 0; i < 16; ++i)
        sS[(r0 + i) * 36 + col] = m2 * fa[i] - ((r0 + i) == col ? sh : 0.f);
    asm volatile("" ::: "memory");

    // ---- Clenshaw on fragments
    float b0f[16], b1f[16];
    float cD = cheb[DDEG];
#pragma unroll
    for (int i = 0; i < 16; ++i) { b0f[i] = ((r0 + i) == col) ? cD : 0.f; b1f[i] = 0.f; }
    for (int k = DDEG - 1; k >= 1; k -= 2) {
        float ck = cheb[k], ck2 = cheb[k - 1];
        CL_HALF(b1f, b0f, ck, 2.0f);
        CL_HALF(b0f, b1f, ck2, 2.0f);
    }
    // final: f = 0.5*c0 I - b_2 + Shat*b_1
    CL_HALF(b1f, b0f, 0.5f * cheb[0], 1.0f);

#pragma unroll
    for (int i = 0; i < 16; ++i) atomicAdd(&sLacc[(r0 + i) * 32 + col], b1f[i]);
    __syncthreads();
    float4 v = *(float4*)&sLacc[4 * t];
    ((float4*)pL)[(size_t)blockIdx.x * 256 + t] = v;
}

// ---------------- K3b: reduce 4096 partials -> 32 ----------------
__global__ __launch_bounds__(256) void k_red32(const float4* __restrict__ pL4,
                                               float4* __restrict__ pL24) {
    int b = blockIdx.x, t = threadIdx.x;
    float4 acc = { 0.f, 0.f, 0.f, 0.f };
    for (int r = 0; r < 128; ++r) {
        float4 v = pL4[(size_t)(b * 128 + r) * 256 + t];
        acc.x += v.x; acc.y += v.y; acc.z += v.z; acc.w += v.w;
    }
    pL24[b * 256 + t] = acc;
}

// ---------------- K4: L -> expL -> Gn -> Gn^{-1/2}; W^{1/2}; C = Wsq*Gn_isq ----------------
__global__ __launch_bounds__(256) void k_final(const float4* __restrict__ pL24,
                                               const float* __restrict__ Wg,
                                               float* __restrict__ ws) {
    __shared__ alignas(16) float B0[1024], B1[1024], B2[1024], B3[1024], B4[1024], B5[1024], B6[1024];
    __shared__ float sc[4];
    int t = threadIdx.x;
    int i = t >> 3, j0 = (t & 7) * 4;
    if (t == 0) { sc[2] = 0.f; }
    float4 acc = { 0.f, 0.f, 0.f, 0.f };
    for (int b = 0; b < 32; ++b) {
        float4 v = pL24[b * 256 + t];
        acc.x += v.x; acc.y += v.y; acc.z += v.z; acc.w += v.w;
    }
    const float invM = 1.0f / (float)NMAT;
    B0[4 * t + 0] = acc.x * invM; B0[4 * t + 1] = acc.y * invM;
    B0[4 * t + 2] = acc.z * invM; B0[4 * t + 3] = acc.w * invM;
    __syncthreads();
    if (t == 0) { float s = 0.f; for (int d = 0; d < 32; ++d) s += B0[d * 33]; sc[0] = s / 32.0f; }
    __syncthreads();
    float s0 = sc[0];
#pragma unroll
    for (int q = 0; q < 4; ++q) {
        int e = i * 32 + j0 + q;
        B1[e] = B0[e] - ((i == j0 + q) ? s0 : 0.f);   // L0
    }
    __syncthreads();
#pragma unroll
    for (int q = 0; q < 4; ++q) {
        int e = i * 32 + j0 + q;
        float d = (i == j0 + q) ? 1.f : 0.f;
        B2[e] = B1[e];
        B4[e] = d + B1[e];
    }
    __syncthreads();
    {
        float* P = B2; float* Pn = B3;
        for (int k = 2; k <= 14; ++k) {
            mm32(P, B1, Pn, t);
            __syncthreads();
            float invk = 1.0f / (float)k;
#pragma unroll
            for (int q = 0; q < 4; ++q) {
                int e = i * 32 + j0 + q;
                Pn[e] *= invk;
                B4[e] += Pn[e];
            }
            float* tmp = P; P = Pn; Pn = tmp;
            __syncthreads();
        }
    }
    float es = expf(s0);
#pragma unroll
    for (int q = 0; q < 4; ++q) B4[i * 32 + j0 + q] *= es;   // expL
    __syncthreads();
    for (int e = t; e < 1024; e += 256) B5[e] = ws[WS_GSQ + e];
    __syncthreads();
    mm32(B5, B4, B6, t); __syncthreads();
    mm32(B6, B5, B0, t); __syncthreads();                    // Gn in B0
    if (t == 0) { float s = 0.f; for (int d = 0; d < 32; ++d) s += B0[d * 33]; sc[1] = s / 32.0f; }
    __syncthreads();
    float c2 = sc[1];
#pragma unroll
    for (int q = 0; q < 4; ++q) {
        int e = i * 32 + j0 + q;
        B2[e] = B0[e] / c2;
        B3[e] = (i == j0 + q) ? 1.f : 0.f;
    }
    __syncthreads();
    {   // coupled NS for Gn/c2: Z->rsqrt
        float* Y = B2; float* Z = B3; float* T = B6; float* Ya = B1; float* Zb = B4;
        for (int it = 0; it < 10; ++it) {
            mm32(Z, Y, T, t); __syncthreads();
#pragma unroll
            for (int q = 0; q < 4; ++q) {
                int e = i * 32 + j0 + q;
                T[e] = 0.5f * (3.f * ((i == j0 + q) ? 1.f : 0.f) - T[e]);
            }
            __syncthreads();
            mm32(Y, T, Ya, t); mm32(T, Z, Zb, t); __syncthreads();
            float* tmp = Y; Y = Ya; Ya = tmp;
            tmp = Z; Z = Zb; Zb = tmp;
        }
        float rc2 = rsqrtf(c2);
#pragma unroll
        for (int q = 0; q < 4; ++q) {
            int e = i * 32 + j0 + q;
            B5[e] = Z[e] * rc2;      // Gn^{-1/2}
        }
    }
    __syncthreads();
    for (int e = t; e < 1024; e += 256) B0[e] = Wg[e];
    __syncthreads();
    {
        float ls = 0.f;
#pragma unroll
        for (int q = 0; q < 4; ++q) { float w = B0[i * 32 + j0 + q]; ls += w * w; }
        atomicAdd(&sc[2], ls);
    }
    __syncthreads();
    float c3 = sqrtf(sc[2]);
#pragma unroll
    for (int q = 0; q < 4; ++q) {
        int e = i * 32 + j0 + q;
        B2[e] = B0[e] / c3;
        B3[e] = (i == j0 + q) ? 1.f : 0.f;
    }
    __syncthreads();
    {
        float* Y = B2; float* Z = B3; float* T = B6; float* Ya = B1; float* Zb = B4;
        for (int it = 0; it < 16; ++it) {
            mm32(Z, Y, T, t); __syncthreads();
#pragma unroll
            for (int q = 0; q < 4; ++q) {
                int e = i * 32 + j0 + q;
                T[e] = 0.5f * (3.f * ((i == j0 + q) ? 1.f : 0.f) - T[e]);
            }
            __syncthreads();
            mm32(Y, T, Ya, t); mm32(T, Z, Zb, t); __syncthreads();
            float* tmp = Y; Y = Ya; Ya = tmp;
            tmp = Z; Z = Zb; Zb = tmp;
        }
        float rc3 = sqrtf(c3);
#pragma unroll
        for (int q = 0; q < 4; ++q) {
            int e = i * 32 + j0 + q;
            B0[e] = Y[e] * rc3;      // W^{1/2}
        }
    }
    __syncthreads();
    mm32(B0, B5, B6, t); __syncthreads();   // C = Wsq * Gn_isq
#pragma unroll
    for (int q = 0; q < 4; ++q) {
        int e = i * 32 + j0 + q;
        ws[WS_C + e] = B6[e];
        ws[WS_CT + (j0 + q) * 32 + i] = B6[e];
    }
}

// ---------------- K5: out = C * X * C^T ----------------
__global__ __launch_bounds__(256) void k_out(const float* __restrict__ Xg,
                                             const float* __restrict__ ws,
                                             float* __restrict__ Og) {
    __shared__ alignas(16) float sCT[1024];
    __shared__ alignas(16) float sX[1024];
    __shared__ alignas(16) float sTt[33 * 32];
    int t = threadIdx.x;
    int i = t >> 3, j0 = (t & 7) * 4;
    for (int e = t; e < 1024; e += 256) sCT[e] = ws[WS_CT + e];
    __syncthreads();
    for (int r = 0; r < 8; ++r) {
        int m = blockIdx.x * 8 + r;
        const float4* Xm4 = (const float4*)(Xg + (size_t)m * 1024);
        *(float4*)&sX[4 * t] = Xm4[t];
        __syncthreads();
        float ax = 0.f, ay = 0.f, az = 0.f, aw = 0.f;
#pragma unroll
        for (int k = 0; k < 32; ++k) {
            float cv = sCT[k * 32 + i];
            float4 xv = *(const float4*)&sX[k * 32 + j0];
            ax += cv * xv.x; ay += cv * xv.y; az += cv * xv.z; aw += cv * xv.w;
        }
        sTt[(j0 + 0) * 33 + i] = ax; sTt[(j0 + 1) * 33 + i] = ay;
        sTt[(j0 + 2) * 33 + i] = az; sTt[(j0 + 3) * 33 + i] = aw;
        __syncthreads();
        ax = ay = az = aw = 0.f;
#pragma unroll
        for (int k = 0; k < 32; ++k) {
            float tv = sTt[k * 33 + i];
            float4 cv = *(const float4*)&sCT[k * 32 + j0];
            ax += tv * cv.x; ay += tv * cv.y; az += tv * cv.z; aw += tv * cv.w;
        }
        float4 r4 = { ax, ay, az, aw };
        *(float4*)&Og[(size_t)m * 1024 + i * 32 + j0] = r4;
        __syncthreads();
    }
}

extern "C" void kernel_launch(void* const* d_in, const int* in_sizes, int n_in,
                              void* d_out, int out_size, void* d_ws, size_t ws_size,
                              hipStream_t stream) {
    const float* X = (const float*)d_in[0];
    const float* W = (const float*)d_in[1];
    float* out = (float*)d_out;
    float* ws  = (float*)d_ws;
    float* pA  = out + OUT_PA;
    float* pL  = out + OUT_PL;
    float* pL2 = out + OUT_PL2;

    hipLaunchKernelGGL(k_psum,   dim3(256),  dim3(256), 0, stream, (const float4*)X, (float4*)pA);
    hipLaunchKernelGGL(k_setup,  dim3(1),    dim3(256), 0, stream, (const float4*)pA, ws);
    hipLaunchKernelGGL(k_logsum, dim3(4096), dim3(256), 0, stream, X, ws, pL);
    hipLaunchKernelGGL(k_red32,  dim3(32),   dim3(256), 0, stream, (const float4*)pL, (float4*)pL2);
    hipLaunchKernelGGL(k_final,  dim3(1),    dim3(256), 0, stream, (const float4*)pL2, W, ws);
    hipLaunchKernelGGL(k_out,    dim3(2048), dim3(256), 0, stream, X, ws, out);
}

// Round 4
// 344.092 us; speedup vs baseline: 71.0094x; 3.3905x over previous
//
#include <hip/hip_runtime.h>
#include <math.h>

#define NMAT   16384
#define CHEB_A 0.08
#define CHEB_B 7.0
#define DDEG   37            // Chebyshev degree (odd); coefficients c_0..c_37
#define NCOEF  (DDEG + 1)
#define NWAVES 3072          // 768 blocks x 4 waves (grid-stride over matrices)

// ws float layout
#define WS_GQ    0
#define WS_GSQ   1024
#define WS_C     2112
#define WS_CT    3136

// d_out float scratch layout (consumed before final kernel overwrites):
#define OUT_PA   0          // 256*1024  (stage-1 partial sums of X)
#define OUT_PL   262144     // 768*1024  (stage-3 partial sums of log)
#define OUT_PL2  1048576    // 32*1024

typedef __attribute__((ext_vector_type(8)))  short short8;   // 8 bf16 (4 VGPRs)
typedef __attribute__((ext_vector_type(16))) float f32x16;   // MFMA 32x32 C/D

union FB { short8 v; unsigned int w[4]; };

// round-half-up f32->bf16, pack pair into one dword (lo=a, hi=b)
__device__ __forceinline__ unsigned int pk2(float a, float b) {
    unsigned int au = __float_as_uint(a) + 0x8000u;
    unsigned int bu = __float_as_uint(b) + 0x8000u;
    return __builtin_amdgcn_perm(bu, au, 0x07060302u);
}
__device__ __forceinline__ float rhi(float x) {   // bf16-rounded value as float
    return __uint_as_float((__float_as_uint(x) + 0x8000u) & 0xffff0000u);
}

// Store D (C/D layout fp32) as bf16 transposed into per-wave Ut (72 B row pitch),
// read back the two B-operand k-half fragments. Wave-internal, no barrier.
template <bool HALF>
__device__ __forceinline__ void toB(const f32x16& d, char* Ut, int col, int h,
                                    FB& b1, FB& b2) {
    char* wp = Ut + col * 72 + h * 8;
#pragma unroll
    for (int g = 0; g < 4; ++g) {
        float s0 = HALF ? 0.5f * d[4 * g + 0] : d[4 * g + 0];
        float s1 = HALF ? 0.5f * d[4 * g + 1] : d[4 * g + 1];
        float s2 = HALF ? 0.5f * d[4 * g + 2] : d[4 * g + 2];
        float s3 = HALF ? 0.5f * d[4 * g + 3] : d[4 * g + 3];
        uint2 wv; wv.x = pk2(s0, s1); wv.y = pk2(s2, s3);
        *(uint2*)(wp + g * 16) = wv;          // rows 8g+4h+0..3 of column col
    }
    __asm__ volatile("" ::: "memory");
    char* rp = Ut + col * 72 + h * 16;
    uint2 r0 = *(const uint2*)(rp);           // k = 8h..8h+3
    uint2 r1 = *(const uint2*)(rp + 8);       // k = 8h+4..8h+7
    uint2 r2 = *(const uint2*)(rp + 32);      // k = 16+8h..
    uint2 r3 = *(const uint2*)(rp + 40);
    b1.w[0] = r0.x; b1.w[1] = r0.y; b1.w[2] = r1.x; b1.w[3] = r1.y;
    b2.w[0] = r2.x; b2.w[1] = r2.y; b2.w[2] = r3.x; b2.w[3] = r3.y;
    __asm__ volatile("" ::: "memory");
}

#define MFMA(a, b, c) __builtin_amdgcn_mfma_f32_32x32x16_bf16((a), (b), (c), 0, 0, 0)

// ---------------- block-level 32x32 matmul on LDS (row-major), 256 threads ----------------
__device__ __forceinline__ void mm32(const float* A, const float* B, float* D, int t) {
    int i = t >> 3, j0 = (t & 7) * 4;
    float a[32];
#pragma unroll
    for (int q = 0; q < 8; ++q) {
        float4 v = *(const float4*)&A[i * 32 + q * 4];
        a[4 * q] = v.x; a[4 * q + 1] = v.y; a[4 * q + 2] = v.z; a[4 * q + 3] = v.w;
    }
    float ax = 0.f, ay = 0.f, az = 0.f, aw = 0.f;
#pragma unroll
    for (int k = 0; k < 32; ++k) {
        float4 bv = *(const float4*)&B[k * 32 + j0];
        ax += a[k] * bv.x; ay += a[k] * bv.y; az += a[k] * bv.z; aw += a[k] * bv.w;
    }
    float4 r = { ax, ay, az, aw };
    *(float4*)&D[i * 32 + j0] = r;
}

// ---------------- K1: partial sums (256 blocks x 64 matrices) ----------------
__global__ __launch_bounds__(256) void k_psum(const float4* __restrict__ X4,
                                              float4* __restrict__ pA4) {
    int b = blockIdx.x, t = threadIdx.x;
    float4 acc = { 0.f, 0.f, 0.f, 0.f };
    for (int r = 0; r < 64; ++r) {
        float4 v = X4[(size_t)(b * 64 + r) * 256 + t];
        acc.x += v.x; acc.y += v.y; acc.z += v.z; acc.w += v.w;
    }
    pA4[b * 256 + t] = acc;
}

// ---------------- K2: finalize G, G^{1/2}, G^{-1/2} ----------------
__global__ __launch_bounds__(256) void k_setup(const float4* __restrict__ pA4,
                                               float* __restrict__ ws) {
    __shared__ alignas(16) float sG[1024], sE[1024], sPa[1024], sPb[1024], sS1[1024], sS2[1024];
    __shared__ float sc[2];
    int t = threadIdx.x;
    float4 acc = { 0.f, 0.f, 0.f, 0.f };
    for (int b = 0; b < 256; ++b) {
        float4 v = pA4[b * 256 + t];
        acc.x += v.x; acc.y += v.y; acc.z += v.z; acc.w += v.w;
    }
    const float invM = 1.0f / (float)NMAT;
    sG[4 * t + 0] = acc.x * invM; sG[4 * t + 1] = acc.y * invM;
    sG[4 * t + 2] = acc.z * invM; sG[4 * t + 3] = acc.w * invM;
    __syncthreads();
    if (t == 0) { float s = 0.f; for (int d = 0; d < 32; ++d) s += sG[d * 33]; sc[0] = s / 32.0f; }
    __syncthreads();
    float c = sc[0];
    int i = t >> 3, j0 = (t & 7) * 4;
#pragma unroll
    for (int q = 0; q < 4; ++q) {
        int e = i * 32 + j0 + q;
        sE[e] = sG[e] / c - ((i == j0 + q) ? 1.f : 0.f);
    }
    __syncthreads();
    const float alp[9] = { 1.f, 0.5f, -0.125f, 0.0625f, -0.0390625f, 0.02734375f,
                           -0.0205078125f, 0.01611328125f, -0.013092041015625f };
    const float bet[9] = { 1.f, -0.5f, 0.375f, -0.3125f, 0.2734375f, -0.24609375f,
                           0.2255859375f, -0.20947265625f, 0.196380615234375f };
#pragma unroll
    for (int q = 0; q < 4; ++q) {
        int e = i * 32 + j0 + q;
        float d = (i == j0 + q) ? 1.f : 0.f;
        sS1[e] = d + alp[1] * sE[e];
        sS2[e] = d + bet[1] * sE[e];
        sPa[e] = sE[e];
    }
    __syncthreads();
    {
        float* P = sPa; float* Pn = sPb;
        for (int k = 2; k <= 8; ++k) {
            mm32(P, sE, Pn, t);
            __syncthreads();
#pragma unroll
            for (int q = 0; q < 4; ++q) {
                int e = i * 32 + j0 + q;
                sS1[e] += alp[k] * Pn[e];
                sS2[e] += bet[k] * Pn[e];
            }
            float* tmp = P; P = Pn; Pn = tmp;
            __syncthreads();
        }
    }
    float rc = sqrtf(c);
#pragma unroll
    for (int q = 0; q < 4; ++q) {
        int e = i * 32 + j0 + q;
        ws[WS_GSQ + e] = rc * sS1[e];
        ws[WS_GQ + e]  = sS2[e] / rc;
    }
}

// ---------------- K3: sum of matrix logs, MFMA Clenshaw ----------------
__global__ __launch_bounds__(256, 3) void k_logsum(const float* __restrict__ Xg,
                                                   const float* __restrict__ ws,
                                                   float* __restrict__ pL) {
    __shared__ alignas(16) char sUt[4 * 2304];
    __shared__ float sLacc[1024];
    __shared__ float scheb[NCOEF];
    int t = threadIdx.x;
    for (int e = t; e < 1024; e += 256) sLacc[e] = 0.f;
    if (t < NCOEF) {
        // closed-form Chebyshev coeffs of log on [a,b]
        float alpha = 0.5f * (float)(CHEB_A + CHEB_B);
        float beta  = 0.5f * (float)(CHEB_B - CHEB_A);
        float dd = beta / alpha, s = sqrtf(1.f - dd * dd), tt = dd / (1.f + s);
        float v;
        if (t == 0) v = 2.f * (logf(alpha) + logf(0.5f * (1.f + s)));
        else        v = 2.f * ((t & 1) ? 1.f : -1.f) * exp2f((float)t * log2f(tt)) / (float)t;
        scheb[t] = v;
    }
    const int wv = t >> 6, lane = t & 63, h = lane >> 5, col = lane & 31;
    char* Ut = sUt + wv * 2304;

    // diagonal mask in C/D layout: row(reg)=(reg&3)+8*(reg>>2)+4h == col
    int hasd = (((col >> 2) & 1) == h);
    int dreg = 4 * (col >> 3) + (col & 3);
    f32x16 dm;
#pragma unroll
    for (int r = 0; r < 16; ++r) dm[r] = (hasd && r == dreg) ? 1.f : 0.f;

    // Gq fragments (symmetric; same regs serve as A- and B-operand), hi/lo split
    const float* Gqp = ws + WS_GQ + col * 32 + 8 * h;
    float4 ga = *(const float4*)(Gqp);
    float4 gb = *(const float4*)(Gqp + 4);
    float4 gc = *(const float4*)(Gqp + 16);
    float4 gd = *(const float4*)(Gqp + 20);
    FB GqH1, GqH2, GqL1, GqL2;
    GqH1.w[0] = pk2(ga.x, ga.y); GqH1.w[1] = pk2(ga.z, ga.w);
    GqH1.w[2] = pk2(gb.x, gb.y); GqH1.w[3] = pk2(gb.z, gb.w);
    GqH2.w[0] = pk2(gc.x, gc.y); GqH2.w[1] = pk2(gc.z, gc.w);
    GqH2.w[2] = pk2(gd.x, gd.y); GqH2.w[3] = pk2(gd.z, gd.w);
    GqL1.w[0] = pk2(ga.x - rhi(ga.x), ga.y - rhi(ga.y));
    GqL1.w[1] = pk2(ga.z - rhi(ga.z), ga.w - rhi(ga.w));
    GqL1.w[2] = pk2(gb.x - rhi(gb.x), gb.y - rhi(gb.y));
    GqL1.w[3] = pk2(gb.z - rhi(gb.z), gb.w - rhi(gb.w));
    GqL2.w[0] = pk2(gc.x - rhi(gc.x), gc.y - rhi(gc.y));
    GqL2.w[1] = pk2(gc.z - rhi(gc.z), gc.w - rhi(gc.w));
    GqL2.w[2] = pk2(gd.x - rhi(gd.x), gd.y - rhi(gd.y));
    GqL2.w[3] = pk2(gd.z - rhi(gd.z), gd.w - rhi(gd.w));
    __syncthreads();   // scheb + sLacc ready

    f32x16 Facc;
#pragma unroll
    for (int r = 0; r < 16; ++r) Facc[r] = 0.f;
    const float m2v = 2.0f / (float)(CHEB_B - CHEB_A);
    const float shv = (float)((CHEB_A + CHEB_B) / (CHEB_B - CHEB_A));
    const float tm = 2.f * m2v, tsh = -2.f * shv;
    const float c37v = scheb[DDEG], c0h = 0.5f * scheb[0];

    for (int m = blockIdx.x * 4 + wv; m < NMAT; m += NWAVES) {
        const float* Xm = Xg + (size_t)m * 1024 + col * 32 + 8 * h;
        float4 xa = *(const float4*)(Xm);
        float4 xb = *(const float4*)(Xm + 4);
        float4 xc = *(const float4*)(Xm + 16);
        float4 xd = *(const float4*)(Xm + 20);
        FB AX1, AX2;
        AX1.w[0] = pk2(xa.x, xa.y); AX1.w[1] = pk2(xa.z, xa.w);
        AX1.w[2] = pk2(xb.x, xb.y); AX1.w[3] = pk2(xb.z, xb.w);
        AX2.w[0] = pk2(xc.x, xc.y); AX2.w[1] = pk2(xc.z, xc.w);
        AX2.w[2] = pk2(xd.x, xd.y); AX2.w[3] = pk2(xd.z, xd.w);

        // U = X * Gq   (X symmetric -> direct A-frags; Gq split hi+lo)
        f32x16 U;
#pragma unroll
        for (int r = 0; r < 16; ++r) U[r] = 0.f;
        U = MFMA(AX2.v, GqL2.v, U); U = MFMA(AX1.v, GqL1.v, U);
        U = MFMA(AX2.v, GqH2.v, U); U = MFMA(AX1.v, GqH1.v, U);
        FB B1, B2;
        toB<false>(U, Ut, col, h, B1, B2);
        // S = Gq * U
        f32x16 S;
#pragma unroll
        for (int r = 0; r < 16; ++r) S[r] = 0.f;
        S = MFMA(GqL2.v, B2.v, S); S = MFMA(GqL1.v, B1.v, S);
        S = MFMA(GqH2.v, B2.v, S); S = MFMA(GqH1.v, B1.v, S);
        // 2*Shat = tm*S + tsh*I  -> A-operand frags (symmetric)
        f32x16 T;
#pragma unroll
        for (int r = 0; r < 16; ++r) T[r] = fmaf(tm, S[r], tsh * dm[r]);
        FB A1, A2;
        toB<false>(T, Ut, col, h, A1, A2);

        // Clenshaw: b_k = c_k I - b_{k+2} + (2Shat)*b_{k+1}
        f32x16 X0, X1;
#pragma unroll
        for (int r = 0; r < 16; ++r) { X1[r] = c37v * dm[r]; X0[r] = 0.f; }
        toB<false>(X1, Ut, col, h, B1, B2);
        for (int it = 0; it < 18; ++it) {
            float ka = scheb[DDEG - 1 - 2 * it];
            float kb = scheb[DDEG - 2 - 2 * it];
#pragma unroll
            for (int r = 0; r < 16; ++r) X0[r] = fmaf(ka, dm[r], -X0[r]);
            X0 = MFMA(A2.v, B2.v, X0); X0 = MFMA(A1.v, B1.v, X0);
            toB<false>(X0, Ut, col, h, B1, B2);
#pragma unroll
            for (int r = 0; r < 16; ++r) X1[r] = fmaf(kb, dm[r], -X1[r]);
            X1 = MFMA(A2.v, B2.v, X1); X1 = MFMA(A1.v, B1.v, X1);
            if (it < 17) toB<false>(X1, Ut, col, h, B1, B2);
            else         toB<true>(X1, Ut, col, h, B1, B2);   // 0.5*b_1
        }
        // f = 0.5*c0 I - b_2 + (2Shat)*(0.5 b_1)
#pragma unroll
        for (int r = 0; r < 16; ++r) X0[r] = fmaf(c0h, dm[r], -X0[r]);
        X0 = MFMA(A2.v, B2.v, X0); X0 = MFMA(A1.v, B1.v, X0);
#pragma unroll
        for (int r = 0; r < 16; ++r) Facc[r] += X0[r];
    }
#pragma unroll
    for (int r = 0; r < 16; ++r) {
        int row = (r & 3) + 8 * (r >> 2) + 4 * h;
        atomicAdd(&sLacc[row * 32 + col], Facc[r]);
    }
    __syncthreads();
    float4 v = *(float4*)&sLacc[4 * t];
    ((float4*)pL)[(size_t)blockIdx.x * 256 + t] = v;
}

// ---------------- K3b: reduce 768 partials -> 32 ----------------
__global__ __launch_bounds__(256) void k_red32(const float4* __restrict__ pL4,
                                               float4* __restrict__ pL24) {
    int b = blockIdx.x, t = threadIdx.x;
    float4 acc = { 0.f, 0.f, 0.f, 0.f };
    for (int r = 0; r < 24; ++r) {
        float4 v = pL4[(size_t)(b * 24 + r) * 256 + t];
        acc.x += v.x; acc.y += v.y; acc.z += v.z; acc.w += v.w;
    }
    pL24[b * 256 + t] = acc;
}

// ---------------- K4: L -> expL -> Gn -> Gn^{-1/2}; W^{1/2}; C = Wsq*Gn_isq ----------------
__global__ __launch_bounds__(256) void k_final(const float4* __restrict__ pL24,
                                               const float* __restrict__ Wg,
                                               float* __restrict__ ws) {
    __shared__ alignas(16) float B0[1024], B1[1024], B2[1024], B3[1024], B4[1024], B5[1024], B6[1024];
    __shared__ float sc[4];
    int t = threadIdx.x;
    int i = t >> 3, j0 = (t & 7) * 4;
    if (t == 0) { sc[2] = 0.f; }
    float4 acc = { 0.f, 0.f, 0.f, 0.f };
    for (int b = 0; b < 32; ++b) {
        float4 v = pL24[b * 256 + t];
        acc.x += v.x; acc.y += v.y; acc.z += v.z; acc.w += v.w;
    }
    const float invM = 1.0f / (float)NMAT;
    B0[4 * t + 0] = acc.x * invM; B0[4 * t + 1] = acc.y * invM;
    B0[4 * t + 2] = acc.z * invM; B0[4 * t + 3] = acc.w * invM;
    __syncthreads();
    if (t == 0) { float s = 0.f; for (int d = 0; d < 32; ++d) s += B0[d * 33]; sc[0] = s / 32.0f; }
    __syncthreads();
    float s0 = sc[0];
#pragma unroll
    for (int q = 0; q < 4; ++q) {
        int e = i * 32 + j0 + q;
        B1[e] = B0[e] - ((i == j0 + q) ? s0 : 0.f);   // L0
    }
    __syncthreads();
#pragma unroll
    for (int q = 0; q < 4; ++q) {
        int e = i * 32 + j0 + q;
        float d = (i == j0 + q) ? 1.f : 0.f;
        B2[e] = B1[e];
        B4[e] = d + B1[e];
    }
    __syncthreads();
    {
        float* P = B2; float* Pn = B3;
        for (int k = 2; k <= 12; ++k) {
            mm32(P, B1, Pn, t);
            __syncthreads();
            float invk = 1.0f / (float)k;
#pragma unroll
            for (int q = 0; q < 4; ++q) {
                int e = i * 32 + j0 + q;
                Pn[e] *= invk;
                B4[e] += Pn[e];
            }
            float* tmp = P; P = Pn; Pn = tmp;
            __syncthreads();
        }
    }
    float es = expf(s0);
#pragma unroll
    for (int q = 0; q < 4; ++q) B4[i * 32 + j0 + q] *= es;   // expL
    __syncthreads();
    for (int e = t; e < 1024; e += 256) B5[e] = ws[WS_GSQ + e];
    __syncthreads();
    mm32(B5, B4, B6, t); __syncthreads();
    mm32(B6, B5, B0, t); __syncthreads();                    // Gn in B0
    if (t == 0) { float s = 0.f; for (int d = 0; d < 32; ++d) s += B0[d * 33]; sc[1] = s / 32.0f; }
    __syncthreads();
    float c2 = sc[1];
#pragma unroll
    for (int q = 0; q < 4; ++q) {
        int e = i * 32 + j0 + q;
        B2[e] = B0[e] / c2;
        B3[e] = (i == j0 + q) ? 1.f : 0.f;
    }
    __syncthreads();
    {   // coupled NS for Gn/c2: Z->rsqrt
        float* Y = B2; float* Z = B3; float* T = B6; float* Ya = B1; float* Zb = B4;
        for (int it = 0; it < 8; ++it) {
            mm32(Z, Y, T, t); __syncthreads();
#pragma unroll
            for (int q = 0; q < 4; ++q) {
                int e = i * 32 + j0 + q;
                T[e] = 0.5f * (3.f * ((i == j0 + q) ? 1.f : 0.f) - T[e]);
            }
            __syncthreads();
            mm32(Y, T, Ya, t); mm32(T, Z, Zb, t); __syncthreads();
            float* tmp = Y; Y = Ya; Ya = tmp;
            tmp = Z; Z = Zb; Zb = tmp;
        }
        float rc2 = rsqrtf(c2);
#pragma unroll
        for (int q = 0; q < 4; ++q) {
            int e = i * 32 + j0 + q;
            B5[e] = Z[e] * rc2;      // Gn^{-1/2}
        }
    }
    __syncthreads();
    for (int e = t; e < 1024; e += 256) B0[e] = Wg[e];
    __syncthreads();
    {
        float ls = 0.f;
#pragma unroll
        for (int q = 0; q < 4; ++q) { float w = B0[i * 32 + j0 + q]; ls += w * w; }
        atomicAdd(&sc[2], ls);
    }
    __syncthreads();
    float c3 = sqrtf(sc[2]);
#pragma unroll
    for (int q = 0; q < 4; ++q) {
        int e = i * 32 + j0 + q;
        B2[e] = B0[e] / c3;
        B3[e] = (i == j0 + q) ? 1.f : 0.f;
    }
    __syncthreads();
    {
        float* Y = B2; float* Z = B3; float* T = B6; float* Ya = B1; float* Zb = B4;
        for (int it = 0; it < 15; ++it) {
            mm32(Z, Y, T, t); __syncthreads();
#pragma unroll
            for (int q = 0; q < 4; ++q) {
                int e = i * 32 + j0 + q;
                T[e] = 0.5f * (3.f * ((i == j0 + q) ? 1.f : 0.f) - T[e]);
            }
            __syncthreads();
            mm32(Y, T, Ya, t); mm32(T, Z, Zb, t); __syncthreads();
            float* tmp = Y; Y = Ya; Ya = tmp;
            tmp = Z; Z = Zb; Zb = tmp;
        }
        float rc3 = sqrtf(c3);
#pragma unroll
        for (int q = 0; q < 4; ++q) {
            int e = i * 32 + j0 + q;
            B0[e] = Y[e] * rc3;      // W^{1/2}
        }
    }
    __syncthreads();
    mm32(B0, B5, B6, t); __syncthreads();   // C = Wsq * Gn_isq
#pragma unroll
    for (int q = 0; q < 4; ++q) {
        int e = i * 32 + j0 + q;
        ws[WS_C + e] = B6[e];
        ws[WS_CT + (j0 + q) * 32 + i] = B6[e];
    }
}

// ---------------- K5: out = C * X * C^T ----------------
__global__ __launch_bounds__(256) void k_out(const float* __restrict__ Xg,
                                             const float* __restrict__ ws,
                                             float* __restrict__ Og) {
    __shared__ alignas(16) float sCT[1024];
    __shared__ alignas(16) float sX[1024];
    __shared__ alignas(16) float sTt[33 * 32];
    int t = threadIdx.x;
    int i = t >> 3, j0 = (t & 7) * 4;
    for (int e = t; e < 1024; e += 256) sCT[e] = ws[WS_CT + e];
    __syncthreads();
    for (int r = 0; r < 8; ++r) {
        int m = blockIdx.x * 8 + r;
        const float4* Xm4 = (const float4*)(Xg + (size_t)m * 1024);
        *(float4*)&sX[4 * t] = Xm4[t];
        __syncthreads();
        float ax = 0.f, ay = 0.f, az = 0.f, aw = 0.f;
#pragma unroll
        for (int k = 0; k < 32; ++k) {
            float cv = sCT[k * 32 + i];
            float4 xv = *(const float4*)&sX[k * 32 + j0];
            ax += cv * xv.x; ay += cv * xv.y; az += cv * xv.z; aw += cv * xv.w;
        }
        sTt[(j0 + 0) * 33 + i] = ax; sTt[(j0 + 1) * 33 + i] = ay;
        sTt[(j0 + 2) * 33 + i] = az; sTt[(j0 + 3) * 33 + i] = aw;
        __syncthreads();
        ax = ay = az = aw = 0.f;
#pragma unroll
        for (int k = 0; k < 32; ++k) {
            float tv = sTt[k * 33 + i];
            float4 cv = *(const float4*)&sCT[k * 32 + j0];
            ax += tv * cv.x; ay += tv * cv.y; az += tv * cv.z; aw += tv * cv.w;
        }
        float4 r4 = { ax, ay, az, aw };
        *(float4*)&Og[(size_t)m * 1024 + i * 32 + j0] = r4;
        __syncthreads();
    }
}

extern "C" void kernel_launch(void* const* d_in, const int* in_sizes, int n_in,
                              void* d_out, int out_size, void* d_ws, size_t ws_size,
                              hipStream_t stream) {
    const float* X = (const float*)d_in[0];
    const float* W = (const float*)d_in[1];
    float* out = (float*)d_out;
    float* ws  = (float*)d_ws;
    float* pA  = out + OUT_PA;
    float* pL  = out + OUT_PL;
    float* pL2 = out + OUT_PL2;

    hipLaunchKernelGGL(k_psum,   dim3(256),  dim3(256), 0, stream, (const float4*)X, (float4*)pA);
    hipLaunchKernelGGL(k_setup,  dim3(1),    dim3(256), 0, stream, (const float4*)pA, ws);
    hipLaunchKernelGGL(k_logsum, dim3(768),  dim3(256), 0, stream, X, ws, pL);
    hipLaunchKernelGGL(k_red32,  dim3(32),   dim3(256), 0, stream, (const float4*)pL, (float4*)pL2);
    hipLaunchKernelGGL(k_final,  dim3(1),    dim3(256), 0, stream, (const float4*)pL2, W, ws);
    hipLaunchKernelGGL(k_out,    dim3(2048), dim3(256), 0, stream, X, ws, out);
}